// Round 4
// baseline (214.029 us; speedup 1.0000x reference)
//
#include <hip/hip_runtime.h>
#include <hip/hip_bf16.h>
#include <stdint.h>

typedef unsigned short u16;
typedef __attribute__((ext_vector_type(8))) short short8;
typedef __attribute__((ext_vector_type(4))) float f32x4;

#define BATCH 4096
#define DIN   1024
#define NH    1024
#define KTOT  2048

__device__ __forceinline__ void gload_lds16(const void* gp, void* lp) {
    __builtin_amdgcn_global_load_lds(
        (const __attribute__((address_space(1))) uint32_t*)gp,
        (__attribute__((address_space(3))) uint32_t*)lp, 16, 0, 0);
}

__device__ __forceinline__ u16 f2bf(float f) {   // round-to-nearest-even
    uint32_t t; __builtin_memcpy(&t, &f, 4);
    uint32_t r = (t + 0x7FFFu + ((t >> 16) & 1u)) >> 16;
    return (u16)r;
}
__device__ __forceinline__ float hsig(float z) {
    return fminf(fmaxf(fmaf(z, 0.2f, 0.5f), 0.0f), 1.0f);
}
__device__ __forceinline__ float fast_tanh(float x) {
    x = fminf(fmaxf(x, -12.0f), 12.0f);
    float e = __expf(2.0f * x);
    return (e - 1.0f) / (e + 1.0f);
}

// ---------------------------------------------------------------------------
// Fused prep kernel (unchanged)
// ---------------------------------------------------------------------------
#define WT_BLOCKS 2048
__global__ __launch_bounds__(256) void prep_kernel(
    const float* __restrict__ x, const float* __restrict__ h0,
    const float* __restrict__ Wf, const float* __restrict__ Wi,
    const float* __restrict__ Wo, const float* __restrict__ Wc,
    const float* __restrict__ Uf, const float* __restrict__ Ui,
    const float* __restrict__ Uo, const float* __restrict__ Uc,
    u16* __restrict__ Bt, u16* __restrict__ Abuf)
{
    __shared__ u16 tile[64][65];
    const int bid = blockIdx.x;
    const int tid = threadIdx.x;

    if (bid < WT_BLOCKS) {
        const int mz = bid >> 8;
        const float* srcs[8] = {Wf, Wi, Wo, Wc, Uf, Ui, Uo, Uc};
        const float* src = srcs[mz];
        const int g    = mz & 3;
        const int koff = (mz >> 2) << 10;
        const int k0 = ((bid >> 4) & 15) * 64;
        const int n0 = (bid & 15) * 64;

#pragma unroll
        for (int i = 0; i < 4; i++) {
            int idx = i * 256 + tid;
            int kk = idx >> 4, c = idx & 15;
            float4 v = *(const float4*)(src + (size_t)(k0 + kk) * NH + n0 + c * 4);
            u16* dst = &tile[kk][c * 4];
            dst[0] = f2bf(v.x); dst[1] = f2bf(v.y);
            dst[2] = f2bf(v.z); dst[3] = f2bf(v.w);
        }
        __syncthreads();
#pragma unroll
        for (int i = 0; i < 2; i++) {
            int idx = i * 256 + tid;
            int nn = idx >> 3, c = idx & 7;
            union { u16 v[8]; uint4 q; } pk;
#pragma unroll
            for (int j = 0; j < 8; j++) pk.v[j] = tile[c * 8 + j][nn];
            *(uint4*)(Bt + ((size_t)(g * NH + n0 + nn)) * KTOT + koff + k0 + c * 8) = pk.q;
        }
    } else {
        const int c  = (bid - WT_BLOCKS) * 256 + tid;
        const int m  = c >> 8;
        const int kc = (c & 255) * 8;
        const float* src = (kc < DIN) ? (x + (size_t)m * DIN + kc)
                                      : (h0 + (size_t)m * DIN + (kc - DIN));
        float4 v0 = *(const float4*)(src);
        float4 v1 = *(const float4*)(src + 4);
        union { u16 v[8]; uint4 q; } pk;
        pk.v[0] = f2bf(v0.x); pk.v[1] = f2bf(v0.y);
        pk.v[2] = f2bf(v0.z); pk.v[3] = f2bf(v0.w);
        pk.v[4] = f2bf(v1.x); pk.v[5] = f2bf(v1.y);
        pk.v[6] = f2bf(v1.z); pk.v[7] = f2bf(v1.w);
        *(uint4*)(Abuf + (size_t)m * KTOT + kc) = pk.q;
    }
}

// ---------------------------------------------------------------------------
// R14 GEMM.  256m x (64n x 4g), BK=64, 8 waves (2m x 4n), acc[8][4].
// Key change vs R13: ds_reads feed the NEXT phase's MFMAs and there is NO
// explicit lgkmcnt(0) -- the compiler emits counted lgkm waits, so the LDS
// pipe serves ahead-reads DURING the MFMA clusters (intra-wave overlap; the
// serial LDS-then-MFMA pattern was the flat-79us bottleneck of R10-R13).
// Quadrant order Q0(A0,B0) Q1(A0,B1) Q2(A1,B1) Q3(A1,B0); reads balanced
// 4/8/8/4 per phase; all frag sets single-buffered (A0(u+1) lands in regs
// A0(u) freed after p1).
// LDS: A ring-3 (3x32KB) + B ring-2 (2x32KB) = 160 KB.  Stage plan during
// tile u: p0: B-lo(u+1); p1: A-lo(u+2); p2: B-hi(u+1); p3: A-hi(u+2).
// vmcnt(4) at ends of p0/p1/p3, each BEFORE the trailing barrier (per-wave
// wait + barrier => all-waves guarantee).  Ledger (pairs = 2 vm-ops):
//   after W3(u-1): landed {B-lo(u), A-lo(u+1)}; outstanding [Bhi(u),Ahi(u+1)]
//   W1@p0(u): outst [Bhi(u),Ahi(u+1),Blo(u+1)]=6 -> drains Bhi(u)
//             => B1(u) readable @p1(u)
//   W2@p1(u): outst [Ahi(u+1),Blo(u+1),Alo(u+2)]=6 -> drains Ahi(u+1)
//             => full A(u+1) readable @p2(u) (both wm halves)
//   W3@p3(u): outst [Blo(u+1),Alo(u+2),Bhi(u+1),Ahi(u+2)]=8 -> drains
//             Blo(u+1)+Alo(u+2) => B0(u+1) readable @p0(u+1)
// Issue-to-forced-landing leads: all >= 2 phases (~1400 cyc > 900-cyc HBM
// miss).  Never drained to 0 in the main loop.  Last 2 tiles peeled with
// vmcnt(0) (prefetch stream ends there anyway).
// XCD swizzle: grid 256 blocks; xcd = lin&7 owns a contiguous 2-n-block
// strip (2 MB of B -> L2-resident per XCD).
// ---------------------------------------------------------------------------
#define BM   256
#define BNG  64
#define BK   64
#define NT   (KTOT / BK)        // 32
#define ATILE 16384             // u16 per A tile (256*64)
#define BTILE 16384
#define BBASE (3 * ATILE)       // B ring starts after A ring-3

__global__ __launch_bounds__(512, 2) void lstm_gemm_kernel(
    const u16* __restrict__ Abuf, const float* __restrict__ c0,
    const u16* __restrict__ Bt,
    const float* __restrict__ bfv, const float* __restrict__ biv,
    const float* __restrict__ bov, const float* __restrict__ bcv,
    float* __restrict__ out)
{
    extern __shared__ u16 smem[];            // 160 KiB dynamic LDS

    const int tid  = threadIdx.x;
    const int wv   = tid >> 6;
    const int lane = tid & 63;
    const int wm = wv >> 2;
    const int wn = wv & 3;

    // XCD-contiguous swizzle (bijective, grid = 16x16 = 256 = 8 XCD x 32)
    const int lin = blockIdx.y * 16 + blockIdx.x;
    const int xcd = lin & 7, j = lin >> 3;
    const int nb  = xcd * 2 + (j & 1);       // n-block 0..15
    const int mb  = j >> 1;                  // m-block 0..15
    const int m0  = mb * BM;
    const int n0  = nb * BNG;

    // ---- staging constants ----
    const int l8   = lane >> 3;
    const int sc   = ((lane & 7) ^ l8) * 8;            // pre-swizzled chunk
    const int rowL = wv * 8 + l8;                      // 0..63
    const u16* gA = Abuf + (size_t)(m0 + rowL) * KTOT + sc;
    const u16* gB = Bt   + (size_t)(n0 + rowL) * KTOT + sc;   // gate-0 row
    const int ldsOff = wv * 512;

    auto stageA = [&](int half, int tt) {    // half0: rows 0-127, half1: 128-255
        u16* ld = smem + (tt % 3) * ATILE + half * 8192 + ldsOff;
        const u16* g = gA + (size_t)tt * BK + (size_t)(half * 128) * KTOT;
        gload_lds16(g, ld);
        gload_lds16(g + (size_t)64 * KTOT, ld + 4096);
    };
    auto stageB = [&](int half, int tt) {    // half0: gates 0-1, half1: 2-3
        u16* ld = smem + BBASE + (tt & 1) * BTILE + half * 8192 + ldsOff;
        const u16* g = gB + (size_t)tt * BK + (size_t)(half * 2) * NH * KTOT;
        gload_lds16(g, ld);
        gload_lds16(g + (size_t)NH * KTOT, ld + 4096);
    };

    // ---- fragment constants ----
    const int am   = lane & 15;
    const int quad = lane >> 4;
    const int a7   = am & 7;
    const int ck0 = (quad ^ a7) * 8;          // un-swizzled k-chunk, kk=0
    const int ck1 = ((4 + quad) ^ a7) * 8;    // kk=1

    f32x4 acc[8][4];
#pragma unroll
    for (int mt = 0; mt < 8; mt++)
#pragma unroll
        for (int g = 0; g < 4; g++)
            acc[mt][g] = (f32x4){0.f, 0.f, 0.f, 0.f};

    short8 a0[4][2], a1[4][2], b0[2][2], b1[2][2];

#define LD8(base, row, ck) (*(const short8*)((base) + (row) * 64 + (ck)))
#define AROW(h, mt) (wm * 128 + (h) * 64 + (mt) * 16 + am)
#define BROW(g)     ((g) * 64 + wn * 16 + am)

    // ---- prologue ----
    stageA(0, 0); stageA(1, 0); stageB(0, 0);   // tile-0 A + B-lo
    stageA(0, 1);                               // A-lo(1)
    asm volatile("s_waitcnt vmcnt(0)");
    __builtin_amdgcn_s_barrier();
    {
        const u16* as0 = smem;                  // tile 0 = A buf 0
#pragma unroll
        for (int mt = 0; mt < 4; mt++) {        // seed A0(0)
            a0[mt][0] = LD8(as0, AROW(0, mt), ck0);
            a0[mt][1] = LD8(as0, AROW(0, mt), ck1);
        }
    }
    stageB(1, 0);                               // B-hi(0)   -> outstanding
    stageA(1, 1);                               // A-hi(1)   -> outstanding

    auto tileBody = [&](int u, bool SB, bool SA, bool RN, bool TAIL) {
        const u16* asp = smem + (u % 3) * ATILE;
        const u16* asn = smem + ((u + 1) % 3) * ATILE;
        const u16* bsp = smem + BBASE + (u & 1) * BTILE;

        // ======== p0: Q0 = (A0,B0) ========
#pragma unroll
        for (int g = 0; g < 2; g++) {           // B0(u), needed this phase
            b0[g][0] = LD8(bsp, BROW(g), ck0);
            b0[g][1] = LD8(bsp, BROW(g), ck1);
        }
        if (SB) stageB(0, u + 1);
        __builtin_amdgcn_s_barrier();
        __builtin_amdgcn_s_setprio(1);
#pragma unroll
        for (int g = 0; g < 2; g++)
#pragma unroll
            for (int mt = 0; mt < 4; mt++)
#pragma unroll
                for (int kk = 0; kk < 2; kk++)
                    acc[mt][g] = __builtin_amdgcn_mfma_f32_16x16x32_bf16(
                        a0[mt][kk], b0[g][kk], acc[mt][g], 0, 0, 0);
        __builtin_amdgcn_s_setprio(0);
        if (TAIL) asm volatile("s_waitcnt vmcnt(0)");   // W1
        else      asm volatile("s_waitcnt vmcnt(4)");
        __builtin_amdgcn_s_barrier();

        // ======== p1: Q1 = (A0,B1) ========
#pragma unroll
        for (int g = 0; g < 2; g++) {           // B1(u), needed this phase
            b1[g][0] = LD8(bsp, BROW(2 + g), ck0);
            b1[g][1] = LD8(bsp, BROW(2 + g), ck1);
        }
#pragma unroll
        for (int mt = 0; mt < 4; mt++)          // A1(u) kk0, needed @p2
            a1[mt][0] = LD8(asp, AROW(1, mt), ck0);
        if (SA) stageA(0, u + 2);
        __builtin_amdgcn_s_barrier();
        __builtin_amdgcn_s_setprio(1);
#pragma unroll
        for (int g = 0; g < 2; g++)
#pragma unroll
            for (int mt = 0; mt < 4; mt++)
#pragma unroll
                for (int kk = 0; kk < 2; kk++)
                    acc[mt][2 + g] = __builtin_amdgcn_mfma_f32_16x16x32_bf16(
                        a0[mt][kk], b1[g][kk], acc[mt][2 + g], 0, 0, 0);
        __builtin_amdgcn_s_setprio(0);
        if (TAIL) asm volatile("s_waitcnt vmcnt(0)");   // W2
        else      asm volatile("s_waitcnt vmcnt(4)");
        __builtin_amdgcn_s_barrier();

        // ======== p2: Q2 = (A1,B1) ========
#pragma unroll
        for (int mt = 0; mt < 4; mt++)          // A1(u) kk1, needed this phase
            a1[mt][1] = LD8(asp, AROW(1, mt), ck1);
        if (RN)
#pragma unroll
            for (int mt = 0; mt < 4; mt++)      // A0(u+1) kk0 (into freed a0)
                a0[mt][0] = LD8(asn, AROW(0, mt), ck0);
        if (SB) stageB(1, u + 1);
        __builtin_amdgcn_s_barrier();
        __builtin_amdgcn_s_setprio(1);
#pragma unroll
        for (int g = 0; g < 2; g++)
#pragma unroll
            for (int mt = 0; mt < 4; mt++)
#pragma unroll
                for (int kk = 0; kk < 2; kk++)
                    acc[4 + mt][2 + g] = __builtin_amdgcn_mfma_f32_16x16x32_bf16(
                        a1[mt][kk], b1[g][kk], acc[4 + mt][2 + g], 0, 0, 0);
        __builtin_amdgcn_s_setprio(0);
        __builtin_amdgcn_s_barrier();

        // ======== p3: Q3 = (A1,B0) ========
        if (RN)
#pragma unroll
            for (int mt = 0; mt < 4; mt++)      // A0(u+1) kk1
                a0[mt][1] = LD8(asn, AROW(0, mt), ck1);
        if (SA) stageA(1, u + 2);
        __builtin_amdgcn_s_barrier();
        __builtin_amdgcn_s_setprio(1);
#pragma unroll
        for (int g = 0; g < 2; g++)
#pragma unroll
            for (int mt = 0; mt < 4; mt++)
#pragma unroll
                for (int kk = 0; kk < 2; kk++)
                    acc[4 + mt][g] = __builtin_amdgcn_mfma_f32_16x16x32_bf16(
                        a1[mt][kk], b0[g][kk], acc[4 + mt][g], 0, 0, 0);
        __builtin_amdgcn_s_setprio(0);
        if (TAIL) asm volatile("s_waitcnt vmcnt(0)");   // W3
        else      asm volatile("s_waitcnt vmcnt(4)");
        __builtin_amdgcn_s_barrier();
    };

    for (int u = 0; u < NT - 2; ++u)
        tileBody(u, true, u + 2 < NT, true, false);
    tileBody(NT - 2, true,  false, true,  true);
    tileBody(NT - 1, false, false, false, true);

    // ---- epilogue: C/D layout col=lane&15, row=quad*4+reg ----
    const int col = n0 + wn * 16 + am;
    const float bb0 = bfv[col], bb1 = biv[col], bb2 = bov[col], bb3 = bcv[col];
    const size_t HN = (size_t)BATCH * NH;

#pragma unroll
    for (int mt = 0; mt < 8; mt++) {
#pragma unroll
        for (int r = 0; r < 4; r++) {
            const int row = m0 + wm * 128 + mt * 16 + quad * 4 + r;
            const size_t off = (size_t)row * NH + col;
            float zf = acc[mt][0][r] + bb0;
            float zi = acc[mt][1][r] + bb1;
            float zo = acc[mt][2][r] + bb2;
            float zc = acc[mt][3][r] + bb3;
            float fg = hsig(zf), ig = hsig(zi), og = hsig(zo);
            float ct = fast_tanh(zc);
            float cn = fg * c0[off] + ig * ct;
            float hn = og * fast_tanh(cn);
            out[off]          = hn;   // h
            out[HN + off]     = cn;   // c
            out[2 * HN + off] = hn;   // h (duplicate output)
        }
    }
#undef LD8
#undef AROW
#undef BROW
}

extern "C" void kernel_launch(void* const* d_in, const int* in_sizes, int n_in,
                              void* d_out, int out_size, void* d_ws, size_t ws_size,
                              hipStream_t stream) {
    const float* x  = (const float*)d_in[0];
    const float* c0 = (const float*)d_in[1];
    const float* h0 = (const float*)d_in[2];
    const float* Wf = (const float*)d_in[3];
    const float* Wi = (const float*)d_in[4];
    const float* Wo = (const float*)d_in[5];
    const float* Wc = (const float*)d_in[6];
    const float* Uf = (const float*)d_in[7];
    const float* Ui = (const float*)d_in[8];
    const float* Uo = (const float*)d_in[9];
    const float* Uc = (const float*)d_in[10];
    const float* bf = (const float*)d_in[11];
    const float* bi = (const float*)d_in[12];
    const float* bo = (const float*)d_in[13];
    const float* bc = (const float*)d_in[14];

    u16* Bt   = (u16*)d_ws;                          // 4096 x 2048 bf16 = 16 MB
    u16* Abuf = (u16*)d_ws + (size_t)4 * NH * KTOT;  // 4096 x 2048 bf16 = 16 MB

    static bool attr_done = false;
    if (!attr_done) {
        (void)hipFuncSetAttribute((const void*)lstm_gemm_kernel,
                                  hipFuncAttributeMaxDynamicSharedMemorySize,
                                  163840);
        attr_done = true;
    }

    prep_kernel<<<WT_BLOCKS + (BATCH * KTOT / 8) / 256, 256, 0, stream>>>(
        x, h0, Wf, Wi, Wo, Wc, Uf, Ui, Uo, Uc, Bt, Abuf);

    dim3 gg(BATCH / BM, NH / BNG);   // 16 x 16 = 256 blocks, 1/CU, 8 waves/CU
    lstm_gemm_kernel<<<gg, 512, 163840, stream>>>(Abuf, c0, Bt, bf, bi, bo, bc,
                                                  (float*)d_out);
}